// Round 2
// baseline (2497.483 us; speedup 1.0000x reference)
//
#include <hip/hip_runtime.h>
#include <hip/hip_bf16.h>
#include <math.h>

#define DIMD 512
#define HEADS 8
#define NBLK 6
#define DFF 2048
#define BATCH 4
#define SEQ 2048
#define NTOK 8192   // BATCH*SEQ
#define DH 64
#define LNEPS 1e-5f

typedef __bf16 bf16;
typedef __bf16 bf16x8 __attribute__((ext_vector_type(8)));
typedef float f32x4 __attribute__((ext_vector_type(4)));

// ---------------- f32 -> bf16 weight conversion (n % 2048 == 0) ----------------
__global__ void k_cvt(const float* __restrict__ in, bf16* __restrict__ out, int n) {
  int i = (blockIdx.x * 256 + threadIdx.x) * 8;
  if (i >= n) return;
  float4 a = *reinterpret_cast<const float4*>(in + i);
  float4 b = *reinterpret_cast<const float4*>(in + i + 4);
  bf16x8 o;
  o[0] = (bf16)a.x; o[1] = (bf16)a.y; o[2] = (bf16)a.z; o[3] = (bf16)a.w;
  o[4] = (bf16)b.x; o[5] = (bf16)b.y; o[6] = (bf16)b.z; o[7] = (bf16)b.w;
  *reinterpret_cast<bf16x8*>(out + i) = o;
}

// ---------------- embedding + positional encoding (f32 in) ----------------
__global__ void k_embed(const int* __restrict__ x, const float* __restrict__ embed,
                        const float* __restrict__ pe, bf16* __restrict__ hb,
                        float* __restrict__ hf) {
  int row = blockIdx.x;              // token index (b*SEQ + t)
  int t = row & (SEQ - 1);
  int tok = x[row];
  int c = threadIdx.x * 2;
  const float* e = embed + (size_t)tok * DIMD;
  const float* p = pe + (size_t)t * DIMD;
  float v0 = e[c] + p[c];
  float v1 = e[c + 1] + p[c + 1];
  size_t o = (size_t)row * DIMD + c;
  hb[o] = (bf16)v0; hb[o + 1] = (bf16)v1;
  hf[o] = v0;       hf[o + 1] = v1;
}

// ---------------- generic MFMA GEMM with fused epilogues ----------------
enum { EPI_QKV = 0, EPI_RES = 1, EPI_GELU = 2, EPI_BIASRES = 3 };

template <int EPI>
__global__ __launch_bounds__(256) void k_gemm(
    const bf16* __restrict__ A, const bf16* __restrict__ W,
    const float* __restrict__ bias, const float* __restrict__ resf,
    bf16* __restrict__ out0, bf16* __restrict__ out1, bf16* __restrict__ out2,
    float* __restrict__ outf, int M, int N, int K) {
  __shared__ bf16 As[64][40];   // pad->40: 16B aligned rows, 2-way banks
  __shared__ bf16 Bt[64][40];   // B transposed: Bt[n][k]
  int tid = threadIdx.x;
  int wave = tid >> 6, lane = tid & 63, quad = lane >> 4, l15 = lane & 15;
  int m0 = blockIdx.y * 64;
  int n0 = blockIdx.x * 64;
  int m_off = (wave >> 1) * 32;
  int n_off = (wave & 1) * 32;

  f32x4 acc[2][2] = {};

  int am = tid >> 2;            // 0..63
  int ak = (tid & 3) * 8;       // 0,8,16,24
  int bn = tid & 63;            // 0..63 (column of W tile)
  int bk = (tid >> 6) * 8;      // 0,8,16,24

  for (int k0 = 0; k0 < K; k0 += 32) {
    bf16x8 av = *reinterpret_cast<const bf16x8*>(A + (size_t)(m0 + am) * K + k0 + ak);
    *reinterpret_cast<bf16x8*>(&As[am][ak]) = av;
    bf16x8 bv;
#pragma unroll
    for (int j = 0; j < 8; ++j)
      bv[j] = W[(size_t)(k0 + bk + j) * N + n0 + bn];   // coalesced across lanes
    *reinterpret_cast<bf16x8*>(&Bt[bn][bk]) = bv;
    __syncthreads();

    bf16x8 afrag[2], bfrag[2];
#pragma unroll
    for (int i = 0; i < 2; ++i)
      afrag[i] = *reinterpret_cast<const bf16x8*>(&As[m_off + i * 16 + l15][quad * 8]);
#pragma unroll
    for (int j = 0; j < 2; ++j)
      bfrag[j] = *reinterpret_cast<const bf16x8*>(&Bt[n_off + j * 16 + l15][quad * 8]);
#pragma unroll
    for (int i = 0; i < 2; ++i)
#pragma unroll
      for (int j = 0; j < 2; ++j)
        acc[i][j] = __builtin_amdgcn_mfma_f32_16x16x32_bf16(afrag[i], bfrag[j], acc[i][j], 0, 0, 0);
    __syncthreads();
  }

#pragma unroll
  for (int i = 0; i < 2; ++i) {
#pragma unroll
    for (int j = 0; j < 2; ++j) {
#pragma unroll
      for (int r = 0; r < 4; ++r) {
        int row = m0 + m_off + i * 16 + quad * 4 + r;
        int col = n0 + n_off + j * 16 + l15;
        float v = acc[i][j][r];
        if (EPI == EPI_QKV) {
          int d = col / 24;
          int rem = col - d * 24;
          int which = rem >> 3;
          int hh = rem & 7;
          int b = row >> 11;
          int t = row & (SEQ - 1);
          int bh = b * HEADS + hh;
          if (which == 0)      out0[((size_t)bh * SEQ + t) * DH + d] = (bf16)v;       // Q [bh][t][d]
          else if (which == 1) out1[((size_t)bh * SEQ + t) * DH + d] = (bf16)v;       // K [bh][t][d]
          else                 out2[((size_t)bh * DH + d) * SEQ + t] = (bf16)v;       // V^T [bh][d][t]
        } else if (EPI == EPI_RES) {
          outf[(size_t)row * N + col] = v + resf[(size_t)row * N + col];
        } else if (EPI == EPI_GELU) {
          float xv = v + bias[col];
          out0[(size_t)row * N + col] = (bf16)(0.5f * xv * (1.0f + erff(xv * 0.70710678118f)));
        } else {  // EPI_BIASRES
          outf[(size_t)row * N + col] = v + bias[col] + resf[(size_t)row * N + col];
        }
      }
    }
  }
}

// ---------------- fused flash attention (bf16 MFMA, online softmax) ----------------
__global__ __launch_bounds__(256) void k_attn(const bf16* __restrict__ q,
                                              const bf16* __restrict__ k,
                                              const bf16* __restrict__ vt,
                                              bf16* __restrict__ out) {
  __shared__ bf16 Ks[32][88];      // [key][feature], stride 88 -> aligned + 2-way banks
  __shared__ bf16 Vt[64][40];      // [dim][key]
  __shared__ bf16 P[4][16][40];    // per-wave P tile [qrow][key]
  int tid = threadIdx.x;
  int wave = tid >> 6, lane = tid & 63, quad = lane >> 4, l15 = lane & 15;
  int qt = blockIdx.x;             // 0..SEQ/64-1
  int bh = blockIdx.y;             // 0..B*H-1
  const bf16* qbase = q + (size_t)bh * SEQ * DH;
  const bf16* kbase = k + (size_t)bh * SEQ * DH;
  const bf16* vbase = vt + (size_t)bh * DH * SEQ;

  int qrow = qt * 64 + wave * 16 + l15;
  bf16x8 qf[2];
  qf[0] = *reinterpret_cast<const bf16x8*>(qbase + (size_t)qrow * DH + quad * 8);
  qf[1] = *reinterpret_cast<const bf16x8*>(qbase + (size_t)qrow * DH + 32 + quad * 8);

  f32x4 Of[4] = {};
  float m_r[4], l_r[4];
#pragma unroll
  for (int r = 0; r < 4; ++r) { m_r[r] = -INFINITY; l_r[r] = 0.f; }

  for (int j0 = 0; j0 < SEQ; j0 += 32) {
    {
      int key = tid >> 3, ch = (tid & 7) * 8;
      bf16x8 kv = *reinterpret_cast<const bf16x8*>(kbase + (size_t)(j0 + key) * DH + ch);
      *reinterpret_cast<bf16x8*>(&Ks[key][ch]) = kv;
      int d = tid >> 2, vc = (tid & 3) * 8;
      bf16x8 vv = *reinterpret_cast<const bf16x8*>(vbase + (size_t)d * SEQ + j0 + vc);
      *reinterpret_cast<bf16x8*>(&Vt[d][vc]) = vv;
    }
    __syncthreads();

    // S(16x32) = Q(16x64) @ K^T(64x32)
    f32x4 s[2] = {};
#pragma unroll
    for (int nt = 0; nt < 2; ++nt)
#pragma unroll
      for (int c = 0; c < 2; ++c) {
        bf16x8 kf = *reinterpret_cast<const bf16x8*>(&Ks[nt * 16 + l15][c * 32 + quad * 8]);
        s[nt] = __builtin_amdgcn_mfma_f32_16x16x32_bf16(qf[c], kf, s[nt], 0, 0, 0);
      }

    float p0[4], p1[4];
#pragma unroll
    for (int r = 0; r < 4; ++r) {
      float a = s[0][r] * 0.125f, b = s[1][r] * 0.125f;   // dh^-0.5
      float mx = fmaxf(a, b);
      mx = fmaxf(mx, __shfl_xor(mx, 1));
      mx = fmaxf(mx, __shfl_xor(mx, 2));
      mx = fmaxf(mx, __shfl_xor(mx, 4));
      mx = fmaxf(mx, __shfl_xor(mx, 8));
      float mnew = fmaxf(m_r[r], mx);
      float alpha = expf(m_r[r] - mnew);
      float e0 = expf(a - mnew), e1 = expf(b - mnew);
      float ls = e0 + e1;
      ls += __shfl_xor(ls, 1);
      ls += __shfl_xor(ls, 2);
      ls += __shfl_xor(ls, 4);
      ls += __shfl_xor(ls, 8);
      l_r[r] = l_r[r] * alpha + ls;
      m_r[r] = mnew;
      p0[r] = e0; p1[r] = e1;
#pragma unroll
      for (int n = 0; n < 4; ++n) Of[n][r] *= alpha;
    }
    // C/D layout -> A-operand layout via LDS round-trip
#pragma unroll
    for (int r = 0; r < 4; ++r) {
      P[wave][quad * 4 + r][l15] = (bf16)p0[r];
      P[wave][quad * 4 + r][16 + l15] = (bf16)p1[r];
    }
    __syncthreads();
    bf16x8 pf = *reinterpret_cast<const bf16x8*>(&P[wave][l15][quad * 8]);
#pragma unroll
    for (int n = 0; n < 4; ++n) {
      bf16x8 vf = *reinterpret_cast<const bf16x8*>(&Vt[n * 16 + l15][quad * 8]);
      Of[n] = __builtin_amdgcn_mfma_f32_16x16x32_bf16(pf, vf, Of[n], 0, 0, 0);
    }
    __syncthreads();
  }

  int b = bh >> 3, hh = bh & 7;
#pragma unroll
  for (int r = 0; r < 4; ++r) {
    int t = qt * 64 + wave * 16 + quad * 4 + r;
    float inv = 1.0f / l_r[r];
#pragma unroll
    for (int n = 0; n < 4; ++n)
      out[((size_t)(b * SEQ + t)) * DIMD + hh * DH + n * 16 + l15] = (bf16)(Of[n][r] * inv);
  }
}

// ---------------- layernorm: f32 in, bf16 + f32 out ----------------
__global__ void k_ln(const float* __restrict__ in, const float* __restrict__ g,
                     const float* __restrict__ b, bf16* __restrict__ outb,
                     float* __restrict__ outf) {
  int wid = (blockIdx.x * blockDim.x + threadIdx.x) >> 6;  // row
  int lane = threadIdx.x & 63;
  const float* row = in + (size_t)wid * DIMD;
  float xs[8];
  float s = 0.f, sq = 0.f;
#pragma unroll
  for (int j = 0; j < 8; ++j) {
    xs[j] = row[lane * 8 + j];
    s += xs[j];
    sq += xs[j] * xs[j];
  }
#pragma unroll
  for (int m = 1; m < 64; m <<= 1) { s += __shfl_xor(s, m); sq += __shfl_xor(sq, m); }
  float mu = s * (1.0f / DIMD);
  float var = sq * (1.0f / DIMD) - mu * mu;
  float rstd = rsqrtf(var + LNEPS);
  bf16x8 ov;
#pragma unroll
  for (int j = 0; j < 8; ++j) {
    int c = lane * 8 + j;
    float y = (xs[j] - mu) * rstd * g[c] + b[c];
    ov[j] = (bf16)y;
    outf[(size_t)wid * DIMD + c] = y;
  }
  *reinterpret_cast<bf16x8*>(outb + (size_t)wid * DIMD + lane * 8) = ov;
}

// ---------------- classifier head: out[row] = h . Whead + bhead (f32 out) ----------------
__global__ void k_head(const bf16* __restrict__ h, const float* __restrict__ w,
                       const float* __restrict__ bh, float* __restrict__ out) {
  int row = (blockIdx.x * blockDim.x + threadIdx.x) >> 6;
  int lane = threadIdx.x & 63;
  bf16x8 xv = *reinterpret_cast<const bf16x8*>(h + (size_t)row * DIMD + lane * 8);
  float s = 0.f;
#pragma unroll
  for (int j = 0; j < 8; ++j) s += (float)xv[j] * w[lane * 8 + j];
#pragma unroll
  for (int m = 1; m < 64; m <<= 1) s += __shfl_xor(s, m);
  if (lane == 0) out[row] = s + bh[0];
}

extern "C" void kernel_launch(void* const* d_in, const int* in_sizes, int n_in,
                              void* d_out, int out_size, void* d_ws, size_t ws_size,
                              hipStream_t stream) {
  const int*   x     = (const int*)d_in[0];
  const float* embed = (const float*)d_in[1];
  const float* pe    = (const float*)d_in[2];
  const float* Wqkv  = (const float*)d_in[3];
  const float* W0    = (const float*)d_in[4];
  const float* g1    = (const float*)d_in[5];
  const float* b1    = (const float*)d_in[6];
  const float* g2    = (const float*)d_in[7];
  const float* b2    = (const float*)d_in[8];
  const float* Wl1   = (const float*)d_in[9];
  const float* bl1   = (const float*)d_in[10];
  const float* Wl2   = (const float*)d_in[11];
  const float* bl2   = (const float*)d_in[12];
  const float* Whead = (const float*)d_in[13];
  const float* bhead = (const float*)d_in[14];
  float* outp = (float*)d_out;

  char* ws = (char*)d_ws;
  size_t off = 0;
  auto alloc = [&](size_t bytes) { void* p = ws + off; off += (bytes + 255) & ~(size_t)255; return p; };
  const size_t ACT = (size_t)NTOK * DIMD;
  const size_t NWQKV = (size_t)NBLK * DIMD * 3 * DIMD;
  const size_t NW0   = (size_t)NBLK * DIMD * DIMD;
  const size_t NWL1  = (size_t)NBLK * DIMD * DFF;
  const size_t NWL2  = (size_t)NBLK * DFF * DIMD;
  bf16*  hb   = (bf16*)alloc(ACT * 2);
  float* hf   = (float*)alloc(ACT * 4);
  bf16*  qb   = (bf16*)alloc(ACT * 2);          // mid aliases q..ao (32 MB)
  bf16*  kb   = (bf16*)alloc(ACT * 2);
  bf16*  vtb  = (bf16*)alloc(ACT * 2);
  bf16*  ao   = (bf16*)alloc(ACT * 2);
  float* r32  = (float*)alloc(ACT * 4);
  bf16*  yb   = (bf16*)alloc(ACT * 2);
  float* yf   = (float*)alloc(ACT * 4);
  bf16*  wqkb = (bf16*)alloc(NWQKV * 2);
  bf16*  w0b  = (bf16*)alloc(NW0 * 2);
  bf16*  wl1b = (bf16*)alloc(NWL1 * 2);
  bf16*  wl2b = (bf16*)alloc(NWL2 * 2);
  bf16*  mid  = qb;                             // [NTOK, DFF] bf16 = 32 MB, reuses q/k/vt/ao

  k_cvt<<<(int)(NWQKV / 2048), 256, 0, stream>>>(Wqkv, wqkb, (int)NWQKV);
  k_cvt<<<(int)(NW0   / 2048), 256, 0, stream>>>(W0,   w0b,  (int)NW0);
  k_cvt<<<(int)(NWL1  / 2048), 256, 0, stream>>>(Wl1,  wl1b, (int)NWL1);
  k_cvt<<<(int)(NWL2  / 2048), 256, 0, stream>>>(Wl2,  wl2b, (int)NWL2);

  k_embed<<<NTOK, 256, 0, stream>>>(x, embed, pe, hb, hf);
  for (int i = 0; i < NBLK; ++i) {
    k_gemm<EPI_QKV><<<dim3(3 * DIMD / 64, NTOK / 64), 256, 0, stream>>>(
        hb, wqkb + (size_t)i * DIMD * 3 * DIMD, nullptr, nullptr,
        qb, kb, vtb, nullptr, NTOK, 3 * DIMD, DIMD);
    k_attn<<<dim3(SEQ / 64, BATCH * HEADS), 256, 0, stream>>>(qb, kb, vtb, ao);
    k_gemm<EPI_RES><<<dim3(DIMD / 64, NTOK / 64), 256, 0, stream>>>(
        ao, w0b + (size_t)i * DIMD * DIMD, nullptr, hf,
        nullptr, nullptr, nullptr, r32, NTOK, DIMD, DIMD);
    k_ln<<<NTOK / 4, 256, 0, stream>>>(r32, g1 + i * DIMD, b1 + i * DIMD, yb, yf);
    k_gemm<EPI_GELU><<<dim3(DFF / 64, NTOK / 64), 256, 0, stream>>>(
        yb, wl1b + (size_t)i * DIMD * DFF, bl1 + (size_t)i * DFF, nullptr,
        mid, nullptr, nullptr, nullptr, NTOK, DFF, DIMD);
    k_gemm<EPI_BIASRES><<<dim3(DIMD / 64, NTOK / 64), 256, 0, stream>>>(
        mid, wl2b + (size_t)i * DFF * DIMD, bl2 + (size_t)i * DIMD, yf,
        nullptr, nullptr, nullptr, r32, NTOK, DIMD, DFF);
    k_ln<<<NTOK / 4, 256, 0, stream>>>(r32, g2 + i * DIMD, b2 + i * DIMD, hb, hf);
  }
  k_head<<<NTOK / 4, 256, 0, stream>>>(hb, Whead, bhead, outp);
}

// Round 3
// 1780.653 us; speedup vs baseline: 1.4026x; 1.4026x over previous
//
#include <hip/hip_runtime.h>
#include <hip/hip_bf16.h>
#include <math.h>

#define DIMD 512
#define HEADS 8
#define NBLK 6
#define DFF 2048
#define BATCH 4
#define SEQ 2048
#define NTOK 8192   // BATCH*SEQ
#define DH 64
#define LNEPS 1e-5f
#define QSCALE 0.1803368801111204f   // 0.125 * log2(e)

typedef __bf16 bf16;
typedef __bf16 bf16x8 __attribute__((ext_vector_type(8)));
typedef __bf16 bf16x4 __attribute__((ext_vector_type(4)));
typedef float f32x4 __attribute__((ext_vector_type(4)));

__device__ __forceinline__ void async16(const void* g, void* l) {
  __builtin_amdgcn_global_load_lds(
      (const __attribute__((address_space(1))) void*)g,
      (__attribute__((address_space(3))) void*)l, 16, 0, 0);
}

// ---------------- f32 [K][N] -> bf16 [N][K] transpose (per layer) ----------------
__global__ void k_cvt_t(const float* __restrict__ in, bf16* __restrict__ out, int K, int N) {
  __shared__ float T[32][33];
  const float* src = in + (size_t)blockIdx.z * K * N;
  bf16* dst = out + (size_t)blockIdx.z * K * N;
  int k0 = blockIdx.y * 32, n0 = blockIdx.x * 32;
  int r = threadIdx.x >> 3, c4 = (threadIdx.x & 7) * 4;
  float4 v = *reinterpret_cast<const float4*>(src + (size_t)(k0 + r) * N + n0 + c4);
  T[r][c4] = v.x; T[r][c4 + 1] = v.y; T[r][c4 + 2] = v.z; T[r][c4 + 3] = v.w;
  __syncthreads();
  bf16x4 o;
  o[0] = (bf16)T[c4][r]; o[1] = (bf16)T[c4 + 1][r];
  o[2] = (bf16)T[c4 + 2][r]; o[3] = (bf16)T[c4 + 3][r];
  *reinterpret_cast<bf16x4*>(dst + (size_t)(n0 + r) * K + k0 + c4) = o;
}

// ---------------- embedding + positional encoding (f32 in) ----------------
__global__ void k_embed(const int* __restrict__ x, const float* __restrict__ embed,
                        const float* __restrict__ pe, bf16* __restrict__ hb,
                        float* __restrict__ hf) {
  int row = blockIdx.x;
  int t = row & (SEQ - 1);
  int tok = x[row];
  int c = threadIdx.x * 2;
  const float* e = embed + (size_t)tok * DIMD;
  const float* p = pe + (size_t)t * DIMD;
  float v0 = e[c] + p[c];
  float v1 = e[c + 1] + p[c + 1];
  size_t o = (size_t)row * DIMD + c;
  hb[o] = (bf16)v0; hb[o + 1] = (bf16)v1;
  hf[o] = v0;       hf[o + 1] = v1;
}

// ---------------- 128x128 MFMA GEMM, m97-style, fused epilogues ----------------
// A: [M][K] bf16 row-major.  Wt: [N][K] bf16 (weights pre-transposed).
enum { EPI_QKV = 0, EPI_RES = 1, EPI_GELU = 2, EPI_BIASRES = 3 };

template <int EPI>
__global__ __launch_bounds__(256) void k_gemm(
    const bf16* __restrict__ A, const bf16* __restrict__ Wt,
    const float* __restrict__ bias, const float* __restrict__ resf,
    bf16* __restrict__ out0, bf16* __restrict__ out1, bf16* __restrict__ out2,
    float* __restrict__ outf, int N, int K) {
  __shared__ bf16 As[128][32];   // unpadded: global_load_lds lane-contiguous
  __shared__ bf16 Bs[128][32];
  int tid = threadIdx.x;
  int w = tid >> 6, lane = tid & 63, quad = lane >> 4, l15 = lane & 15;
  int m0 = blockIdx.y * 128, n0 = blockIdx.x * 128;
  int wr = w >> 1, wc = w & 1;

  int srow = w * 32 + (lane >> 2);       // staging row (call c adds +16)
  int sk = (lane & 3) * 8;
  const bf16* Ag = A + (size_t)(m0 + srow) * K + sk;
  const bf16* Bg = Wt + (size_t)(n0 + srow) * K + sk;
  bf16* AsU = &As[0][0] + (size_t)w * 1024;   // wave-uniform LDS dest
  bf16* BsU = &Bs[0][0] + (size_t)w * 1024;

  f32x4 acc[4][4] = {};

  for (int k0 = 0; k0 < K; k0 += 32) {
    async16(Ag + k0, AsU);
    async16(Ag + k0 + (size_t)16 * K, AsU + 512);
    async16(Bg + k0, BsU);
    async16(Bg + k0 + (size_t)16 * K, BsU + 512);
    __syncthreads();

    bf16x8 af[4], bfr[4];
#pragma unroll
    for (int i = 0; i < 4; ++i)
      af[i] = *reinterpret_cast<const bf16x8*>(&As[wr * 64 + i * 16 + l15][quad * 8]);
#pragma unroll
    for (int j = 0; j < 4; ++j)
      bfr[j] = *reinterpret_cast<const bf16x8*>(&Bs[wc * 64 + j * 16 + l15][quad * 8]);
#pragma unroll
    for (int i = 0; i < 4; ++i)
#pragma unroll
      for (int j = 0; j < 4; ++j)
        acc[i][j] = __builtin_amdgcn_mfma_f32_16x16x32_bf16(af[i], bfr[j], acc[i][j], 0, 0, 0);
    __syncthreads();
  }

#pragma unroll
  for (int i = 0; i < 4; ++i) {
#pragma unroll
    for (int j = 0; j < 4; ++j) {
#pragma unroll
      for (int r = 0; r < 4; ++r) {
        int row = m0 + wr * 64 + i * 16 + quad * 4 + r;
        int col = n0 + wc * 64 + j * 16 + l15;
        float v = acc[i][j][r];
        if (EPI == EPI_QKV) {
          int d = col / 24;
          int rem = col - d * 24;
          int which = rem >> 3;
          int hh = rem & 7;
          int b = row >> 11;
          int t = row & (SEQ - 1);
          int bh = b * HEADS + hh;
          if (which == 0)      out0[((size_t)bh * SEQ + t) * DH + d] = (bf16)(v * QSCALE);
          else if (which == 1) out1[((size_t)bh * SEQ + t) * DH + d] = (bf16)v;
          else                 out2[((size_t)bh * DH + d) * SEQ + t] = (bf16)v;
        } else if (EPI == EPI_RES) {
          outf[(size_t)row * N + col] = v + resf[(size_t)row * N + col];
        } else if (EPI == EPI_GELU) {
          float xv = v + bias[col];
          out0[(size_t)row * N + col] = (bf16)(0.5f * xv * (1.0f + erff(xv * 0.70710678118f)));
        } else {
          outf[(size_t)row * N + col] = v + bias[col] + resf[(size_t)row * N + col];
        }
      }
    }
  }
}

// ---------------- flash attention, S^T formulation ----------------
// Q pre-scaled by 0.125*log2e; softmax via exp2. Per-lane = one query row.
__global__ __launch_bounds__(256) void k_attn(const bf16* __restrict__ q,
                                              const bf16* __restrict__ k,
                                              const bf16* __restrict__ vt,
                                              bf16* __restrict__ out) {
  __shared__ bf16 Ks[64][72];     // [key][d]
  __shared__ bf16 Vs[64][72];     // [d][key]
  __shared__ bf16 Pw[4][16][72];  // per-wave [qrow][key]; reused for O transpose
  int tid = threadIdx.x;
  int w = tid >> 6, lane = tid & 63, quad = lane >> 4, l15 = lane & 15;
  int qt = blockIdx.x, bh = blockIdx.y;
  const bf16* qbase = q + (size_t)bh * SEQ * DH;
  const bf16* kbase = k + (size_t)bh * SEQ * DH;
  const bf16* vbase = vt + (size_t)bh * DH * SEQ;

  int qrow = qt * 64 + w * 16 + l15;
  bf16x8 qf[2];
  qf[0] = *reinterpret_cast<const bf16x8*>(qbase + (size_t)qrow * DH + quad * 8);
  qf[1] = *reinterpret_cast<const bf16x8*>(qbase + (size_t)qrow * DH + 32 + quad * 8);

  f32x4 Ot[4] = {};
  float m_r = -INFINITY, l_r = 0.f;
  int srow = tid >> 2;            // 0..63
  int scol = (tid & 3) * 16;      // 0,16,32,48

  for (int j0 = 0; j0 < SEQ; j0 += 64) {
    bf16x8 ka = *reinterpret_cast<const bf16x8*>(kbase + (size_t)(j0 + srow) * DH + scol);
    bf16x8 kb = *reinterpret_cast<const bf16x8*>(kbase + (size_t)(j0 + srow) * DH + scol + 8);
    bf16x8 va = *reinterpret_cast<const bf16x8*>(vbase + (size_t)srow * SEQ + j0 + scol);
    bf16x8 vb = *reinterpret_cast<const bf16x8*>(vbase + (size_t)srow * SEQ + j0 + scol + 8);
    __syncthreads();   // previous iteration's frag reads done
    *reinterpret_cast<bf16x8*>(&Ks[srow][scol]) = ka;
    *reinterpret_cast<bf16x8*>(&Ks[srow][scol + 8]) = kb;
    *reinterpret_cast<bf16x8*>(&Vs[srow][scol]) = va;
    *reinterpret_cast<bf16x8*>(&Vs[srow][scol + 8]) = vb;
    __syncthreads();

    // S^T(64x16) = K(64x64) @ Q^T : st[nt][r] = S^T[key=16nt+quad*4+r][qrow=l15]
    f32x4 st[4];
#pragma unroll
    for (int nt = 0; nt < 4; ++nt) {
      bf16x8 kf0 = *reinterpret_cast<const bf16x8*>(&Ks[nt * 16 + l15][quad * 8]);
      bf16x8 kf1 = *reinterpret_cast<const bf16x8*>(&Ks[nt * 16 + l15][32 + quad * 8]);
      f32x4 z = {};
      z = __builtin_amdgcn_mfma_f32_16x16x32_bf16(kf0, qf[0], z, 0, 0, 0);
      z = __builtin_amdgcn_mfma_f32_16x16x32_bf16(kf1, qf[1], z, 0, 0, 0);
      st[nt] = z;
    }

    // online softmax in base-2; per-lane scalar state (lane = query row)
    f32x4 vm0, vm1;
#pragma unroll
    for (int r = 0; r < 4; ++r) { vm0[r] = fmaxf(st[0][r], st[1][r]); vm1[r] = fmaxf(st[2][r], st[3][r]); }
    float tmax = -INFINITY;
#pragma unroll
    for (int r = 0; r < 4; ++r) tmax = fmaxf(tmax, fmaxf(vm0[r], vm1[r]));
    tmax = fmaxf(tmax, __shfl_xor(tmax, 16));
    tmax = fmaxf(tmax, __shfl_xor(tmax, 32));
    float mnew = fmaxf(m_r, tmax);
    float alpha = exp2f(m_r - mnew);
    float ls = 0.f;
#pragma unroll
    for (int nt = 0; nt < 4; ++nt)
#pragma unroll
      for (int r = 0; r < 4; ++r) {
        float p = exp2f(st[nt][r] - mnew);
        st[nt][r] = p;
        ls += p;
      }
    ls += __shfl_xor(ls, 16);
    ls += __shfl_xor(ls, 32);
    l_r = l_r * alpha + ls;
    m_r = mnew;

    // P -> LDS [qrow][key] (packed b64 writes); same-wave read, no barrier
#pragma unroll
    for (int nt = 0; nt < 4; ++nt) {
      bf16x4 pv;
      pv[0] = (bf16)st[nt][0]; pv[1] = (bf16)st[nt][1];
      pv[2] = (bf16)st[nt][2]; pv[3] = (bf16)st[nt][3];
      *reinterpret_cast<bf16x4*>(&Pw[w][l15][nt * 16 + quad * 4]) = pv;
    }
#pragma unroll
    for (int nt = 0; nt < 4; ++nt)
#pragma unroll
      for (int r = 0; r < 4; ++r) Ot[nt][r] *= alpha;

    // O^T += V^T @ P^T : Ot[nt][r] = O^T[d=16nt+quad*4+r][qrow=l15]
#pragma unroll
    for (int h = 0; h < 2; ++h) {
      bf16x8 pf = *reinterpret_cast<const bf16x8*>(&Pw[w][l15][h * 32 + quad * 8]);
#pragma unroll
      for (int nt = 0; nt < 4; ++nt) {
        bf16x8 vf = *reinterpret_cast<const bf16x8*>(&Vs[nt * 16 + l15][h * 32 + quad * 8]);
        Ot[nt] = __builtin_amdgcn_mfma_f32_16x16x32_bf16(vf, pf, Ot[nt], 0, 0, 0);
      }
    }
  }

  // normalize + transpose O^T -> O via per-wave LDS, coalesced b128 stores
  float inv = 1.0f / l_r;
#pragma unroll
  for (int nt = 0; nt < 4; ++nt) {
    bf16x4 ov;
    ov[0] = (bf16)(Ot[nt][0] * inv); ov[1] = (bf16)(Ot[nt][1] * inv);
    ov[2] = (bf16)(Ot[nt][2] * inv); ov[3] = (bf16)(Ot[nt][3] * inv);
    *reinterpret_cast<bf16x4*>(&Pw[w][l15][nt * 16 + quad * 4]) = ov;
  }
  int qr = lane >> 2, c0 = (lane & 3) * 16;
  bf16x8 o0 = *reinterpret_cast<const bf16x8*>(&Pw[w][qr][c0]);
  bf16x8 o1 = *reinterpret_cast<const bf16x8*>(&Pw[w][qr][c0 + 8]);
  int b = bh >> 3, hh = bh & 7;
  int token = b * SEQ + qt * 64 + w * 16 + qr;
  *reinterpret_cast<bf16x8*>(out + (size_t)token * DIMD + hh * DH + c0) = o0;
  *reinterpret_cast<bf16x8*>(out + (size_t)token * DIMD + hh * DH + c0 + 8) = o1;
}

// ---------------- layernorm: f32 in, bf16 + f32 out ----------------
__global__ void k_ln(const float* __restrict__ in, const float* __restrict__ g,
                     const float* __restrict__ b, bf16* __restrict__ outb,
                     float* __restrict__ outf) {
  int wid = (blockIdx.x * blockDim.x + threadIdx.x) >> 6;
  int lane = threadIdx.x & 63;
  const float* row = in + (size_t)wid * DIMD;
  float4 x0 = *reinterpret_cast<const float4*>(row + lane * 8);
  float4 x1 = *reinterpret_cast<const float4*>(row + lane * 8 + 4);
  float xs[8] = {x0.x, x0.y, x0.z, x0.w, x1.x, x1.y, x1.z, x1.w};
  float s = 0.f, sq = 0.f;
#pragma unroll
  for (int j = 0; j < 8; ++j) { s += xs[j]; sq += xs[j] * xs[j]; }
#pragma unroll
  for (int m = 1; m < 64; m <<= 1) { s += __shfl_xor(s, m); sq += __shfl_xor(sq, m); }
  float mu = s * (1.0f / DIMD);
  float var = sq * (1.0f / DIMD) - mu * mu;
  float rstd = rsqrtf(var + LNEPS);
  bf16x8 ov;
#pragma unroll
  for (int j = 0; j < 8; ++j) {
    int c = lane * 8 + j;
    float y = (xs[j] - mu) * rstd * g[c] + b[c];
    ov[j] = (bf16)y;
    outf[(size_t)wid * DIMD + c] = y;
  }
  *reinterpret_cast<bf16x8*>(outb + (size_t)wid * DIMD + lane * 8) = ov;
}

// ---------------- classifier head ----------------
__global__ void k_head(const bf16* __restrict__ h, const float* __restrict__ w,
                       const float* __restrict__ bh, float* __restrict__ out) {
  int row = (blockIdx.x * blockDim.x + threadIdx.x) >> 6;
  int lane = threadIdx.x & 63;
  bf16x8 xv = *reinterpret_cast<const bf16x8*>(h + (size_t)row * DIMD + lane * 8);
  float s = 0.f;
#pragma unroll
  for (int j = 0; j < 8; ++j) s += (float)xv[j] * w[lane * 8 + j];
#pragma unroll
  for (int m = 1; m < 64; m <<= 1) s += __shfl_xor(s, m);
  if (lane == 0) out[row] = s + bh[0];
}

extern "C" void kernel_launch(void* const* d_in, const int* in_sizes, int n_in,
                              void* d_out, int out_size, void* d_ws, size_t ws_size,
                              hipStream_t stream) {
  const int*   x     = (const int*)d_in[0];
  const float* embed = (const float*)d_in[1];
  const float* pe    = (const float*)d_in[2];
  const float* Wqkv  = (const float*)d_in[3];
  const float* W0    = (const float*)d_in[4];
  const float* g1    = (const float*)d_in[5];
  const float* b1    = (const float*)d_in[6];
  const float* g2    = (const float*)d_in[7];
  const float* b2    = (const float*)d_in[8];
  const float* Wl1   = (const float*)d_in[9];
  const float* bl1   = (const float*)d_in[10];
  const float* Wl2   = (const float*)d_in[11];
  const float* bl2   = (const float*)d_in[12];
  const float* Whead = (const float*)d_in[13];
  const float* bhead = (const float*)d_in[14];
  float* outp = (float*)d_out;

  char* ws = (char*)d_ws;
  size_t off = 0;
  auto alloc = [&](size_t bytes) { void* p = ws + off; off += (bytes + 255) & ~(size_t)255; return p; };
  const size_t ACT = (size_t)NTOK * DIMD;
  bf16*  hb   = (bf16*)alloc(ACT * 2);
  float* hf   = (float*)alloc(ACT * 4);
  bf16*  qb   = (bf16*)alloc(ACT * 2);
  bf16*  kb   = (bf16*)alloc(ACT * 2);
  bf16*  vtb  = (bf16*)alloc(ACT * 2);
  bf16*  ao   = (bf16*)alloc(ACT * 2);
  float* r32  = (float*)alloc(ACT * 4);
  bf16*  yb   = (bf16*)alloc(ACT * 2);
  float* yf   = (float*)alloc(ACT * 4);
  bf16*  wqkt = (bf16*)alloc((size_t)NBLK * DIMD * 3 * DIMD * 2);  // [L][1536][512]
  bf16*  w0t  = (bf16*)alloc((size_t)NBLK * DIMD * DIMD * 2);      // [L][512][512]
  bf16*  wl1t = (bf16*)alloc((size_t)NBLK * DIMD * DFF * 2);       // [L][2048][512]
  bf16*  wl2t = (bf16*)alloc((size_t)NBLK * DFF * DIMD * 2);       // [L][512][2048]
  bf16*  mid  = qb;   // [NTOK][DFF] bf16 = 32 MB, aliases q/k/vt/ao

  k_cvt_t<<<dim3(3 * DIMD / 32, DIMD / 32, NBLK), 256, 0, stream>>>(Wqkv, wqkt, DIMD, 3 * DIMD);
  k_cvt_t<<<dim3(DIMD / 32, DIMD / 32, NBLK), 256, 0, stream>>>(W0, w0t, DIMD, DIMD);
  k_cvt_t<<<dim3(DFF / 32, DIMD / 32, NBLK), 256, 0, stream>>>(Wl1, wl1t, DIMD, DFF);
  k_cvt_t<<<dim3(DIMD / 32, DFF / 32, NBLK), 256, 0, stream>>>(Wl2, wl2t, DFF, DIMD);

  k_embed<<<NTOK, 256, 0, stream>>>(x, embed, pe, hb, hf);
  for (int i = 0; i < NBLK; ++i) {
    k_gemm<EPI_QKV><<<dim3(3 * DIMD / 128, NTOK / 128), 256, 0, stream>>>(
        hb, wqkt + (size_t)i * DIMD * 3 * DIMD, nullptr, nullptr,
        qb, kb, vtb, nullptr, 3 * DIMD, DIMD);
    k_attn<<<dim3(SEQ / 64, BATCH * HEADS), 256, 0, stream>>>(qb, kb, vtb, ao);
    k_gemm<EPI_RES><<<dim3(DIMD / 128, NTOK / 128), 256, 0, stream>>>(
        ao, w0t + (size_t)i * DIMD * DIMD, nullptr, hf,
        nullptr, nullptr, nullptr, r32, DIMD, DIMD);
    k_ln<<<NTOK / 4, 256, 0, stream>>>(r32, g1 + i * DIMD, b1 + i * DIMD, yb, yf);
    k_gemm<EPI_GELU><<<dim3(DFF / 128, NTOK / 128), 256, 0, stream>>>(
        yb, wl1t + (size_t)i * DIMD * DFF, bl1 + (size_t)i * DFF, nullptr,
        mid, nullptr, nullptr, nullptr, DFF, DIMD);
    k_gemm<EPI_BIASRES><<<dim3(DIMD / 128, NTOK / 128), 256, 0, stream>>>(
        mid, wl2t + (size_t)i * DFF * DIMD, bl2 + (size_t)i * DIMD, yf,
        nullptr, nullptr, nullptr, r32, DIMD, DFF);
    k_ln<<<NTOK / 4, 256, 0, stream>>>(r32, g2 + i * DIMD, b2 + i * DIMD, hb, hf);
  }
  k_head<<<NTOK / 4, 256, 0, stream>>>(hb, Whead, bhead, outp);
}